// Round 8
// baseline (789.542 us; speedup 1.0000x reference)
//
#include <hip/hip_runtime.h>

#define HDIM 128
#define NB   1024     // sort buckets (bucket = r >> BSH; 100000 rows -> 782 used)
#define BSH  7

typedef __bf16 bf16_t;
typedef bf16_t bf16x8 __attribute__((ext_vector_type(8)));
typedef float  f32x4  __attribute__((ext_vector_type(4)));

__device__ __forceinline__ unsigned short f2bf_rne(float f) {
    unsigned int u = __float_as_uint(f);
    u += 0x7fffu + ((u >> 16) & 1u);   // round-to-nearest-even
    return (unsigned short)(u >> 16);
}
__device__ __forceinline__ unsigned int pk_bf2(float a, float b) {
    return (unsigned int)f2bf_rne(a) | ((unsigned int)f2bf_rne(b) << 16);
}

// W1 [2*128 k][128 n] fp32 -> Wt [2][n=128][k=128] bf16 (n-major, k-contiguous)
__global__ __launch_bounds__(256) void convert_w1(
    const float* __restrict__ W1, unsigned short* __restrict__ Wt)
{
    const int o = blockIdx.x * 256 + threadIdx.x;     // 0..32767
    const int g = o >> 14, rem = o & 16383, n = rem >> 7, k = rem & 127;
    Wt[o] = f2bf_rne(W1[g * 16384 + k * 128 + n]);
}

// ===== gemm (v6, unchanged — retro-solved ~49 us, best of 6 variants) ======
__global__ __launch_bounds__(256) void node_gemm_v6(
    const float* __restrict__ Zs, const float* __restrict__ Zd,
    const unsigned short* __restrict__ Wt, const float* __restrict__ b1,
    unsigned short* __restrict__ Abuf, unsigned short* __restrict__ Bbuf,
    int M, int tiles_per_half)
{
    __shared__ unsigned short wlds[128 * 128];   // 32 KB

    const bool second = (blockIdx.x >= tiles_per_half);
    const int tile = second ? (blockIdx.x - tiles_per_half) : blockIdx.x;
    const float* __restrict__ Z          = second ? Zd : Zs;
    const unsigned short* __restrict__ W = Wt + (second ? 128 * 128 : 0);
    unsigned short* __restrict__ C       = second ? Bbuf : Abuf;
    const int t    = threadIdx.x;
    const int lane = t & 63;
    const int wave = t >> 6;
    const int m    = lane & 15;
    const int quad = lane >> 4;

    const int r  = tile * 64 + wave * 16 + m;
    const int rc = (r < M) ? r : (M - 1);
    const float* zrow = Z + (size_t)rc * HDIM;
    float4 zv[4][2];
    #pragma unroll
    for (int ks = 0; ks < 4; ++ks) {
        zv[ks][0] = *reinterpret_cast<const float4*>(zrow + ks * 32 + quad * 8);
        zv[ks][1] = *reinterpret_cast<const float4*>(zrow + ks * 32 + quad * 8 + 4);
    }

    #pragma unroll
    for (int j = 0; j < 8; ++j) {
        const int u = t + 256 * j;
        const int n = u >> 4, cc = u & 15;
        const uint4 v = *reinterpret_cast<const uint4*>(W + n * 128 + cc * 8);
        *reinterpret_cast<uint4*>(wlds + n * 128 + (cc ^ (n & 7)) * 8) = v;
    }
    __syncthreads();

    union { unsigned int u[4]; bf16x8 h; } zf[4];
    #pragma unroll
    for (int ks = 0; ks < 4; ++ks) {
        zf[ks].u[0] = pk_bf2(zv[ks][0].x, zv[ks][0].y);
        zf[ks].u[1] = pk_bf2(zv[ks][0].z, zv[ks][0].w);
        zf[ks].u[2] = pk_bf2(zv[ks][1].x, zv[ks][1].y);
        zf[ks].u[3] = pk_bf2(zv[ks][1].z, zv[ks][1].w);
    }

    f32x4 acc[8] = {};
    #pragma unroll
    for (int ks = 0; ks < 4; ++ks) {
        const int cidx = (ks * 4 + quad) ^ (m & 7);
        #pragma unroll
        for (int ct = 0; ct < 8; ++ct) {
            const bf16x8 wf = *reinterpret_cast<const bf16x8*>(
                wlds + (ct * 16 + m) * 128 + cidx * 8);
            acc[ct] = __builtin_amdgcn_mfma_f32_16x16x32_bf16(
                wf, zf[ks].h, acc[ct], 0, 0, 0);
        }
    }

    if (r < M) {
        unsigned short* crow = C + (size_t)r * HDIM;
        #pragma unroll
        for (int ct = 0; ct < 8; ++ct) {
            const int col = ct * 16 + quad * 4;
            float4 bv = make_float4(0.f, 0.f, 0.f, 0.f);
            if (second) bv = *reinterpret_cast<const float4*>(b1 + col);
            uint2 o;
            o.x = pk_bf2(acc[ct][0] + bv.x, acc[ct][1] + bv.y);
            o.y = pk_bf2(acc[ct][2] + bv.z, acc[ct][3] + bv.w);
            *reinterpret_cast<uint2*>(crow + col) = o;
        }
    }
}

// ===== edge sort-by-row (counting sort, bucket = r>>7) =====================
__global__ __launch_bounds__(256) void zero_cnt(int* __restrict__ p, int n)
{
    const int i = blockIdx.x * 256 + threadIdx.x;
    if (i < n) p[i] = 0;
}

__global__ __launch_bounds__(256) void edge_hist(
    const int* __restrict__ rows, int* __restrict__ cnt, int E)
{
    __shared__ int h[NB];
    for (int i = threadIdx.x; i < NB; i += 256) h[i] = 0;
    __syncthreads();
    for (int e = blockIdx.x * 256 + threadIdx.x; e < E; e += gridDim.x * 256)
        atomicAdd(&h[rows[e] >> BSH], 1);
    __syncthreads();
    for (int i = threadIdx.x; i < NB; i += 256) {
        const int v = h[i];
        if (v) atomicAdd(&cnt[i], v);
    }
}

__global__ __launch_bounds__(NB) void scan_off(
    const int* __restrict__ cnt, int* __restrict__ off)
{
    __shared__ int s[NB];
    const int t = threadIdx.x;
    const int c0 = cnt[t];
    s[t] = c0;
    __syncthreads();
    for (int d = 1; d < NB; d <<= 1) {
        const int v = (t >= d) ? s[t - d] : 0;
        __syncthreads();
        s[t] += v;
        __syncthreads();
    }
    off[t] = s[t] - c0;     // exclusive prefix
}

__global__ __launch_bounds__(256) void edge_scatter(
    const int* __restrict__ rows, const int* __restrict__ cols,
    int* __restrict__ off, int2* __restrict__ rc, int* __restrict__ og, int E)
{
    for (int e = blockIdx.x * 256 + threadIdx.x; e < E; e += gridDim.x * 256) {
        const int r = rows[e];
        const int c = cols[e];
        const int p = atomicAdd(&off[r >> BSH], 1);
        if (p < E) {                       // safety clamp (replay robustness)
            rc[p] = make_int2(r, c);
            og[p] = e;
        }
    }
}

// ===== decode over row-sorted edges =======================================
// Contiguous chunk per 16-lane group: a node's ~20 consecutive edges land in
// 1-2 groups -> A-row fetched once (L1-hot after first touch) instead of ~10x.
// B-side stays random (relu(A_r+B_c) is not separable). out scattered via og.
__global__ __launch_bounds__(256) void edge_decode_sorted(
    const unsigned short* __restrict__ A, const unsigned short* __restrict__ Bm,
    const int2* __restrict__ rc, const int* __restrict__ og,
    const float* __restrict__ W2, const float* __restrict__ b2,
    float* __restrict__ out, int E, int chunk)
{
    const int t   = threadIdx.x;
    const int sub = t & 15;
    const int grp = t >> 4;

    float w2r[8];
    #pragma unroll
    for (int i = 0; i < 8; ++i) w2r[i] = W2[sub * 8 + i];
    const float b2s = b2[0];

    const int gid = blockIdx.x * 16 + grp;
    const int i0  = gid * chunk;
    const int i1  = min(i0 + chunk, E);

    for (int i = i0; i < i1; ++i) {
        const int2 p = rc[i];
        const uint4 av = *reinterpret_cast<const uint4*>(A  + (size_t)p.x * HDIM + sub * 8);
        const uint4 bv = *reinterpret_cast<const uint4*>(Bm + (size_t)p.y * HDIM + sub * 8);

        float s = 0.f;
        #pragma unroll
        for (int k = 0; k < 4; ++k) {
            const unsigned int ua = (&av.x)[k];
            const unsigned int ub = (&bv.x)[k];
            s += fmaxf(__uint_as_float(ua << 16)         + __uint_as_float(ub << 16),         0.f) * w2r[2 * k];
            s += fmaxf(__uint_as_float(ua & 0xffff0000u) + __uint_as_float(ub & 0xffff0000u), 0.f) * w2r[2 * k + 1];
        }
        s += __shfl_xor(s, 1);
        s += __shfl_xor(s, 2);
        s += __shfl_xor(s, 4);
        s += __shfl_xor(s, 8);
        if (sub == 0) out[og[i]] = s + b2s;
    }
}

// fallback (ws too small): original decode, single dispatch
__global__ __launch_bounds__(256) void edge_decode_bf16(
    const unsigned short* __restrict__ A, const unsigned short* __restrict__ Bm,
    const int* __restrict__ idx,
    const float* __restrict__ W2, const float* __restrict__ b2,
    float* __restrict__ out, int E)
{
    const int t   = threadIdx.x;
    const int sub = t & 15;
    const int grp = t >> 4;

    float w2r[8];
    #pragma unroll
    for (int i = 0; i < 8; ++i) w2r[i] = W2[sub * 8 + i];
    const float b2s = b2[0];

    const int stride = gridDim.x * 16;
    for (int e = blockIdx.x * 16 + grp; e < E; e += stride) {
        const int r = idx[e];
        const int c = idx[E + e];
        const uint4 av = *reinterpret_cast<const uint4*>(A  + (size_t)r * HDIM + sub * 8);
        const uint4 bv = *reinterpret_cast<const uint4*>(Bm + (size_t)c * HDIM + sub * 8);

        float s = 0.f;
        #pragma unroll
        for (int i = 0; i < 4; ++i) {
            const unsigned int ua = (&av.x)[i];
            const unsigned int ub = (&bv.x)[i];
            s += fmaxf(__uint_as_float(ua << 16)         + __uint_as_float(ub << 16),         0.f) * w2r[2 * i];
            s += fmaxf(__uint_as_float(ua & 0xffff0000u) + __uint_as_float(ub & 0xffff0000u), 0.f) * w2r[2 * i + 1];
        }
        s += __shfl_xor(s, 1);
        s += __shfl_xor(s, 2);
        s += __shfl_xor(s, 4);
        s += __shfl_xor(s, 8);
        if (sub == 0) out[e] = s + b2s;
    }
}

extern "C" void kernel_launch(void* const* d_in, const int* in_sizes, int n_in,
                              void* d_out, int out_size, void* d_ws, size_t ws_size,
                              hipStream_t stream)
{
    const float* z_src = (const float*)d_in[0];
    const float* z_dst = (const float*)d_in[1];
    const int*   eidx  = (const int*)d_in[2];
    const float* W1    = (const float*)d_in[3];
    const float* b1    = (const float*)d_in[4];
    const float* W2    = (const float*)d_in[5];
    const float* b2    = (const float*)d_in[6];
    float*       outp  = (float*)d_out;

    const int Nn = in_sizes[0] / HDIM;    // 100000
    const int E  = in_sizes[2] / 2;       // 2000000

    unsigned short* Abuf = (unsigned short*)d_ws;
    unsigned short* Bbuf = Abuf + (size_t)Nn * HDIM;
    unsigned short* Wt   = Bbuf + (size_t)Nn * HDIM;
    int*  cnt = (int*)(Wt + 2 * 128 * 128);
    int*  off = cnt + NB;
    int2* rc  = (int2*)(off + NB);
    int*  og  = (int*)(rc + (size_t)E);

    const size_t need = (size_t)((char*)(og + E) - (char*)d_ws);

    convert_w1<<<128, 256, 0, stream>>>(W1, Wt);

    const int tiles = (Nn + 63) >> 6;     // 1563
    node_gemm_v6<<<2 * tiles, 256, 0, stream>>>(
        z_src, z_dst, Wt, b1, Abuf, Bbuf, Nn, tiles);

    if (ws_size >= need) {
        // ---- counting sort by row bucket, then locality-friendly decode ----
        zero_cnt<<<(2 * NB + 255) / 256, 256, 0, stream>>>(cnt, 2 * NB);
        edge_hist<<<512, 256, 0, stream>>>(eidx, cnt, E);
        scan_off<<<1, NB, 0, stream>>>(cnt, off);
        edge_scatter<<<2048, 256, 0, stream>>>(eidx, eidx + E, off, rc, og, E);
        const int groups = 8192 * 16;
        const int chunk  = (E + groups - 1) / groups;   // 16
        edge_decode_sorted<<<8192, 256, 0, stream>>>(
            Abuf, Bbuf, rc, og, W2, b2, outp, E, chunk);
    } else {
        edge_decode_bf16<<<8192, 256, 0, stream>>>(
            Abuf, Bbuf, eidx, W2, b2, outp, E);
    }
}

// Round 9
// 323.085 us; speedup vs baseline: 2.4438x; 2.4438x over previous
//
#include <hip/hip_runtime.h>

#define HDIM 128
#define NB   128      // sort buckets; bucket = r >> BSH (1024 rows = 256 KB A-window, L2-resident)
#define BSH  10
#define NSB  256      // sort blocks (hist/scatter share this chunking)

typedef __bf16 bf16_t;
typedef bf16_t bf16x8 __attribute__((ext_vector_type(8)));
typedef float  f32x4  __attribute__((ext_vector_type(4)));

__device__ __forceinline__ unsigned short f2bf_rne(float f) {
    unsigned int u = __float_as_uint(f);
    u += 0x7fffu + ((u >> 16) & 1u);   // round-to-nearest-even
    return (unsigned short)(u >> 16);
}
__device__ __forceinline__ unsigned int pk_bf2(float a, float b) {
    return (unsigned int)f2bf_rne(a) | ((unsigned int)f2bf_rne(b) << 16);
}

// W1 [2*128 k][128 n] fp32 -> Wt [2][n=128][k=128] bf16 (n-major, k-contiguous)
__global__ __launch_bounds__(256) void convert_w1(
    const float* __restrict__ W1, unsigned short* __restrict__ Wt)
{
    const int o = blockIdx.x * 256 + threadIdx.x;     // 0..32767
    const int g = o >> 14, rem = o & 16383, n = rem >> 7, k = rem & 127;
    Wt[o] = f2bf_rne(W1[g * 16384 + k * 128 + n]);
}

// ===== gemm (v6, unchanged — retro-solved ~49 us, best of 6 variants) ======
__global__ __launch_bounds__(256) void node_gemm_v6(
    const float* __restrict__ Zs, const float* __restrict__ Zd,
    const unsigned short* __restrict__ Wt, const float* __restrict__ b1,
    unsigned short* __restrict__ Abuf, unsigned short* __restrict__ Bbuf,
    int M, int tiles_per_half)
{
    __shared__ unsigned short wlds[128 * 128];   // 32 KB

    const bool second = (blockIdx.x >= tiles_per_half);
    const int tile = second ? (blockIdx.x - tiles_per_half) : blockIdx.x;
    const float* __restrict__ Z          = second ? Zd : Zs;
    const unsigned short* __restrict__ W = Wt + (second ? 128 * 128 : 0);
    unsigned short* __restrict__ C       = second ? Bbuf : Abuf;
    const int t    = threadIdx.x;
    const int lane = t & 63;
    const int wave = t >> 6;
    const int m    = lane & 15;
    const int quad = lane >> 4;

    const int r  = tile * 64 + wave * 16 + m;
    const int rc = (r < M) ? r : (M - 1);
    const float* zrow = Z + (size_t)rc * HDIM;
    float4 zv[4][2];
    #pragma unroll
    for (int ks = 0; ks < 4; ++ks) {
        zv[ks][0] = *reinterpret_cast<const float4*>(zrow + ks * 32 + quad * 8);
        zv[ks][1] = *reinterpret_cast<const float4*>(zrow + ks * 32 + quad * 8 + 4);
    }

    #pragma unroll
    for (int j = 0; j < 8; ++j) {
        const int u = t + 256 * j;
        const int n = u >> 4, cc = u & 15;
        const uint4 v = *reinterpret_cast<const uint4*>(W + n * 128 + cc * 8);
        *reinterpret_cast<uint4*>(wlds + n * 128 + (cc ^ (n & 7)) * 8) = v;
    }
    __syncthreads();

    union { unsigned int u[4]; bf16x8 h; } zf[4];
    #pragma unroll
    for (int ks = 0; ks < 4; ++ks) {
        zf[ks].u[0] = pk_bf2(zv[ks][0].x, zv[ks][0].y);
        zf[ks].u[1] = pk_bf2(zv[ks][0].z, zv[ks][0].w);
        zf[ks].u[2] = pk_bf2(zv[ks][1].x, zv[ks][1].y);
        zf[ks].u[3] = pk_bf2(zv[ks][1].z, zv[ks][1].w);
    }

    f32x4 acc[8] = {};
    #pragma unroll
    for (int ks = 0; ks < 4; ++ks) {
        const int cidx = (ks * 4 + quad) ^ (m & 7);
        #pragma unroll
        for (int ct = 0; ct < 8; ++ct) {
            const bf16x8 wf = *reinterpret_cast<const bf16x8*>(
                wlds + (ct * 16 + m) * 128 + cidx * 8);
            acc[ct] = __builtin_amdgcn_mfma_f32_16x16x32_bf16(
                wf, zf[ks].h, acc[ct], 0, 0, 0);
        }
    }

    if (r < M) {
        unsigned short* crow = C + (size_t)r * HDIM;
        #pragma unroll
        for (int ct = 0; ct < 8; ++ct) {
            const int col = ct * 16 + quad * 4;
            float4 bv = make_float4(0.f, 0.f, 0.f, 0.f);
            if (second) bv = *reinterpret_cast<const float4*>(b1 + col);
            uint2 o;
            o.x = pk_bf2(acc[ct][0] + bv.x, acc[ct][1] + bv.y);
            o.y = pk_bf2(acc[ct][2] + bv.z, acc[ct][3] + bv.w);
            *reinterpret_cast<uint2*>(crow + col) = o;
        }
    }
}

// ===== atomic-free counting sort by row bucket =============================
// R8's scatter died on 2M global atomics over 782 hot addresses (471 us,
// VALUBusy 0.14%). v2: per-block LDS hist -> bcnt[NSB][NB]; deterministic
// per-block bases boff; scatter via LDS-atomic local counters into disjoint
// global ranges. Zero global atomics.

__global__ __launch_bounds__(256) void hist_block(
    const int* __restrict__ rows, int* __restrict__ bcnt, int E, int chunk)
{
    __shared__ int h[NB];
    for (int i = threadIdx.x; i < NB; i += 256) h[i] = 0;
    __syncthreads();
    const int b  = blockIdx.x;
    const int i0 = b * chunk, i1 = min(i0 + chunk, E);
    for (int e = i0 + threadIdx.x; e < i1; e += 256)
        atomicAdd(&h[rows[e] >> BSH], 1);          // LDS atomic
    __syncthreads();
    for (int i = threadIdx.x; i < NB; i += 256)
        bcnt[b * NB + i] = h[i];
}

// single block, NB threads: bucket totals -> exclusive scan -> per-block bases
__global__ __launch_bounds__(NB) void scan_boff(
    const int* __restrict__ bcnt, int* __restrict__ boff)   // boff[NSB][NB]
{
    __shared__ int s[NB];
    const int t = threadIdx.x;
    int tot = 0;
    for (int b = 0; b < NSB; ++b) tot += bcnt[b * NB + t];  // coalesced
    s[t] = tot;
    __syncthreads();
    #pragma unroll
    for (int d = 1; d < NB; d <<= 1) {
        const int v = (t >= d) ? s[t - d] : 0;
        __syncthreads();
        s[t] += v;
        __syncthreads();
    }
    int run = s[t] - tot;                 // exclusive prefix of bucket t
    for (int b = 0; b < NSB; ++b) {       // coalesced writes
        boff[b * NB + t] = run;
        run += bcnt[b * NB + t];
    }
}

__global__ __launch_bounds__(256) void edge_scatter_v2(
    const int* __restrict__ rows, const int* __restrict__ cols,
    const int* __restrict__ boff,
    int2* __restrict__ rc, int* __restrict__ og, int E, int chunk)
{
    __shared__ int base[NB];
    const int b = blockIdx.x;
    for (int i = threadIdx.x; i < NB; i += 256) base[i] = boff[b * NB + i];
    __syncthreads();
    const int i0 = b * chunk, i1 = min(i0 + chunk, E);
    for (int e = i0 + threadIdx.x; e < i1; e += 256) {
        const int r = rows[e];
        const int c = cols[e];
        const int p = atomicAdd(&base[r >> BSH], 1);   // LDS atomic, ranges disjoint
        rc[p] = make_int2(r, c);
        og[p] = e;
    }
}

// ===== decode over bucket-sorted edges =====================================
// Consecutive sorted edges share a 1024-row (256 KB) A-window -> L2-hit after
// first touch. T1 XCD-swizzle keeps each window on 1-2 XCD L2s (without it,
// round-robin spreads every bucket across all 8 XCDs and A-traffic x8).
__global__ __launch_bounds__(256) void edge_decode_sorted(
    const unsigned short* __restrict__ A, const unsigned short* __restrict__ Bm,
    const int2* __restrict__ rc, const int* __restrict__ og,
    const float* __restrict__ W2, const float* __restrict__ b2,
    float* __restrict__ out, int E, int chunk)
{
    const int t   = threadIdx.x;
    const int sub = t & 15;
    const int grp = t >> 4;

    float w2r[8];
    #pragma unroll
    for (int i = 0; i < 8; ++i) w2r[i] = W2[sub * 8 + i];
    const float b2s = b2[0];

    // XCD-aware bijective swizzle (gridDim.x must be a multiple of 8)
    const int cpx = gridDim.x >> 3;
    const int lb  = (blockIdx.x & 7) * cpx + (blockIdx.x >> 3);
    const int gid = lb * 16 + grp;
    const int i0  = gid * chunk;
    const int i1  = min(i0 + chunk, E);

    for (int i = i0; i < i1; ++i) {
        const int2 p = rc[i];
        const uint4 av = *reinterpret_cast<const uint4*>(A  + (size_t)p.x * HDIM + sub * 8);
        const uint4 bv = *reinterpret_cast<const uint4*>(Bm + (size_t)p.y * HDIM + sub * 8);

        float s = 0.f;
        #pragma unroll
        for (int k = 0; k < 4; ++k) {
            const unsigned int ua = (&av.x)[k];
            const unsigned int ub = (&bv.x)[k];
            s += fmaxf(__uint_as_float(ua << 16)         + __uint_as_float(ub << 16),         0.f) * w2r[2 * k];
            s += fmaxf(__uint_as_float(ua & 0xffff0000u) + __uint_as_float(ub & 0xffff0000u), 0.f) * w2r[2 * k + 1];
        }
        s += __shfl_xor(s, 1);
        s += __shfl_xor(s, 2);
        s += __shfl_xor(s, 4);
        s += __shfl_xor(s, 8);
        if (sub == 0) out[og[i]] = s + b2s;
    }
}

// fallback (ws too small): original decode, single dispatch
__global__ __launch_bounds__(256) void edge_decode_bf16(
    const unsigned short* __restrict__ A, const unsigned short* __restrict__ Bm,
    const int* __restrict__ idx,
    const float* __restrict__ W2, const float* __restrict__ b2,
    float* __restrict__ out, int E)
{
    const int t   = threadIdx.x;
    const int sub = t & 15;
    const int grp = t >> 4;

    float w2r[8];
    #pragma unroll
    for (int i = 0; i < 8; ++i) w2r[i] = W2[sub * 8 + i];
    const float b2s = b2[0];

    const int stride = gridDim.x * 16;
    for (int e = blockIdx.x * 16 + grp; e < E; e += stride) {
        const int r = idx[e];
        const int c = idx[E + e];
        const uint4 av = *reinterpret_cast<const uint4*>(A  + (size_t)r * HDIM + sub * 8);
        const uint4 bv = *reinterpret_cast<const uint4*>(Bm + (size_t)c * HDIM + sub * 8);

        float s = 0.f;
        #pragma unroll
        for (int i = 0; i < 4; ++i) {
            const unsigned int ua = (&av.x)[i];
            const unsigned int ub = (&bv.x)[i];
            s += fmaxf(__uint_as_float(ua << 16)         + __uint_as_float(ub << 16),         0.f) * w2r[2 * i];
            s += fmaxf(__uint_as_float(ua & 0xffff0000u) + __uint_as_float(ub & 0xffff0000u), 0.f) * w2r[2 * i + 1];
        }
        s += __shfl_xor(s, 1);
        s += __shfl_xor(s, 2);
        s += __shfl_xor(s, 4);
        s += __shfl_xor(s, 8);
        if (sub == 0) out[e] = s + b2s;
    }
}

extern "C" void kernel_launch(void* const* d_in, const int* in_sizes, int n_in,
                              void* d_out, int out_size, void* d_ws, size_t ws_size,
                              hipStream_t stream)
{
    const float* z_src = (const float*)d_in[0];
    const float* z_dst = (const float*)d_in[1];
    const int*   eidx  = (const int*)d_in[2];
    const float* W1    = (const float*)d_in[3];
    const float* b1    = (const float*)d_in[4];
    const float* W2    = (const float*)d_in[5];
    const float* b2    = (const float*)d_in[6];
    float*       outp  = (float*)d_out;

    const int Nn = in_sizes[0] / HDIM;    // 100000
    const int E  = in_sizes[2] / 2;       // 2000000

    unsigned short* Abuf = (unsigned short*)d_ws;
    unsigned short* Bbuf = Abuf + (size_t)Nn * HDIM;
    unsigned short* Wt   = Bbuf + (size_t)Nn * HDIM;
    int*  bcnt = (int*)(Wt + 2 * 128 * 128);
    int*  boff = bcnt + NSB * NB;
    int2* rc   = (int2*)(boff + NSB * NB);
    int*  og   = (int*)(rc + (size_t)E);

    const size_t need = (size_t)((char*)(og + E) - (char*)d_ws);

    convert_w1<<<128, 256, 0, stream>>>(W1, Wt);

    const int tiles = (Nn + 63) >> 6;     // 1563
    node_gemm_v6<<<2 * tiles, 256, 0, stream>>>(
        z_src, z_dst, Wt, b1, Abuf, Bbuf, Nn, tiles);

    if (ws_size >= need) {
        const int chunk_s = (E + NSB - 1) / NSB;       // 7813
        hist_block<<<NSB, 256, 0, stream>>>(eidx, bcnt, E, chunk_s);
        scan_boff<<<1, NB, 0, stream>>>(bcnt, boff);
        edge_scatter_v2<<<NSB, 256, 0, stream>>>(
            eidx, eidx + E, boff, rc, og, E, chunk_s);
        const int groups  = 8192 * 16;
        const int chunk_d = (E + groups - 1) / groups; // 16
        edge_decode_sorted<<<8192, 256, 0, stream>>>(
            Abuf, Bbuf, rc, og, W2, b2, outp, E, chunk_d);
    } else {
        edge_decode_bf16<<<8192, 256, 0, stream>>>(
            Abuf, Bbuf, eidx, W2, b2, outp, E);
    }
}

// Round 10
// 293.422 us; speedup vs baseline: 2.6908x; 1.1011x over previous
//
#include <hip/hip_runtime.h>

#define HDIM 128

typedef __bf16 bf16_t;
typedef bf16_t bf16x8 __attribute__((ext_vector_type(8)));
typedef float  f32x4  __attribute__((ext_vector_type(4)));

__device__ __forceinline__ unsigned short f2bf_rne(float f) {
    unsigned int u = __float_as_uint(f);
    u += 0x7fffu + ((u >> 16) & 1u);   // round-to-nearest-even
    return (unsigned short)(u >> 16);
}
__device__ __forceinline__ unsigned int pk_bf2(float a, float b) {
    return (unsigned int)f2bf_rne(a) | ((unsigned int)f2bf_rne(b) << 16);
}

// W1 [2*128 k][128 n] fp32 -> Wt [2][n=128][k=128] bf16 (n-major, k-contiguous)
__global__ __launch_bounds__(256) void convert_w1(
    const float* __restrict__ W1, unsigned short* __restrict__ Wt)
{
    const int o = blockIdx.x * 256 + threadIdx.x;     // 0..32767
    const int g = o >> 14, rem = o & 16383, n = rem >> 7, k = rem & 127;
    Wt[o] = f2bf_rne(W1[g * 16384 + k * 128 + n]);
}

// C_bf16[M,128] = bf16(Z[M,128]) @ bf16(W[128,128]) (+ b1 if second half).
// v6, byte-identical to R4 (best measured total, 291.4): one 64-row tile
// per block; W staged once, XOR-swizzled chunks (T2); Z loads issued before
// the stage so HBM latency hides under it. Retro-solved ~49 us; 7 structural
// variants (LDS/reg-W/launder/256-row/pipelined/fused) all within noise or
// worse — treated as structurally converged.
__global__ __launch_bounds__(256) void node_gemm_v6(
    const float* __restrict__ Zs, const float* __restrict__ Zd,
    const unsigned short* __restrict__ Wt, const float* __restrict__ b1,
    unsigned short* __restrict__ Abuf, unsigned short* __restrict__ Bbuf,
    int M, int tiles_per_half)
{
    __shared__ unsigned short wlds[128 * 128];   // 32 KB

    const bool second = (blockIdx.x >= tiles_per_half);
    const int tile = second ? (blockIdx.x - tiles_per_half) : blockIdx.x;
    const float* __restrict__ Z          = second ? Zd : Zs;
    const unsigned short* __restrict__ W = Wt + (second ? 128 * 128 : 0);
    unsigned short* __restrict__ C       = second ? Bbuf : Abuf;
    const int t    = threadIdx.x;
    const int lane = t & 63;
    const int wave = t >> 6;
    const int m    = lane & 15;     // Z row within wave's 16 / D col group
    const int quad = lane >> 4;

    // ---- issue Z loads first (HBM latency hides under W staging) ----
    const int r  = tile * 64 + wave * 16 + m;
    const int rc = (r < M) ? r : (M - 1);
    const float* zrow = Z + (size_t)rc * HDIM;
    float4 zv[4][2];
    #pragma unroll
    for (int ks = 0; ks < 4; ++ks) {
        zv[ks][0] = *reinterpret_cast<const float4*>(zrow + ks * 32 + quad * 8);
        zv[ks][1] = *reinterpret_cast<const float4*>(zrow + ks * 32 + quad * 8 + 4);
    }

    // ---- stage W (128 rows x 16 chunks of 16B), XOR-swizzled chunks ----
    #pragma unroll
    for (int j = 0; j < 8; ++j) {
        const int u = t + 256 * j;          // 0..2047
        const int n = u >> 4, cc = u & 15;
        const uint4 v = *reinterpret_cast<const uint4*>(W + n * 128 + cc * 8);
        *reinterpret_cast<uint4*>(wlds + n * 128 + (cc ^ (n & 7)) * 8) = v;
    }
    __syncthreads();

    // ---- pack Z to bf16 fragments ----
    union { unsigned int u[4]; bf16x8 h; } zf[4];
    #pragma unroll
    for (int ks = 0; ks < 4; ++ks) {
        zf[ks].u[0] = pk_bf2(zv[ks][0].x, zv[ks][0].y);
        zf[ks].u[1] = pk_bf2(zv[ks][0].z, zv[ks][0].w);
        zf[ks].u[2] = pk_bf2(zv[ks][1].x, zv[ks][1].y);
        zf[ks].u[3] = pk_bf2(zv[ks][1].z, zv[ks][1].w);
    }

    // ---- MFMA: acc[ct] += W[ct*16+m, ks*32..] * z ----
    f32x4 acc[8] = {};
    #pragma unroll
    for (int ks = 0; ks < 4; ++ks) {
        const int cidx = (ks * 4 + quad) ^ (m & 7);   // swizzled 16B-chunk
        #pragma unroll
        for (int ct = 0; ct < 8; ++ct) {
            const bf16x8 wf = *reinterpret_cast<const bf16x8*>(
                wlds + (ct * 16 + m) * 128 + cidx * 8);
            acc[ct] = __builtin_amdgcn_mfma_f32_16x16x32_bf16(
                wf, zf[ks].h, acc[ct], 0, 0, 0);
        }
    }

    // ---- epilogue: +bias, fp32->bf16, 8-B stores ----
    if (r < M) {
        unsigned short* crow = C + (size_t)r * HDIM;
        #pragma unroll
        for (int ct = 0; ct < 8; ++ct) {
            const int col = ct * 16 + quad * 4;
            float4 bv = make_float4(0.f, 0.f, 0.f, 0.f);
            if (second) bv = *reinterpret_cast<const float4*>(b1 + col);
            uint2 o;
            o.x = pk_bf2(acc[ct][0] + bv.x, acc[ct][1] + bv.y);
            o.y = pk_bf2(acc[ct][2] + bv.z, acc[ct][3] + bv.w);
            *reinterpret_cast<uint2*>(crow + col) = o;
        }
    }
}

// out[e] = relu(A[row[e]] + B[col[e]]) . W2 + b2, A/B bf16 (b1 folded into B).
// 16 lanes per edge; lane handles 8 features (16 B load/operand).
// R4 body + non-temporal hints on streamed-once data (idx loads, out store):
// idx is 16 MB/iter of L2 pollution competing with the 51 MB A/B gather
// working set; nt keeps those lines from displacing A/B rows.
__global__ __launch_bounds__(256) void edge_decode_bf16(
    const unsigned short* __restrict__ A, const unsigned short* __restrict__ Bm,
    const int* __restrict__ idx,   // [2*E]: rows then cols (int32)
    const float* __restrict__ W2, const float* __restrict__ b2,
    float* __restrict__ out, int E)
{
    const int t   = threadIdx.x;
    const int sub = t & 15;
    const int grp = t >> 4;

    float w2r[8];
    #pragma unroll
    for (int i = 0; i < 8; ++i) w2r[i] = W2[sub * 8 + i];
    const float b2s = b2[0];

    const int stride = gridDim.x * 16;
    for (int e = blockIdx.x * 16 + grp; e < E; e += stride) {
        const int r = __builtin_nontemporal_load(idx + e);
        const int c = __builtin_nontemporal_load(idx + E + e);
        const uint4 av = *reinterpret_cast<const uint4*>(A  + (size_t)r * HDIM + sub * 8);
        const uint4 bv = *reinterpret_cast<const uint4*>(Bm + (size_t)c * HDIM + sub * 8);

        float s = 0.f;
        #pragma unroll
        for (int i = 0; i < 4; ++i) {
            const unsigned int ua = (&av.x)[i];
            const unsigned int ub = (&bv.x)[i];
            s += fmaxf(__uint_as_float(ua << 16)         + __uint_as_float(ub << 16),         0.f) * w2r[2 * i];
            s += fmaxf(__uint_as_float(ua & 0xffff0000u) + __uint_as_float(ub & 0xffff0000u), 0.f) * w2r[2 * i + 1];
        }
        s += __shfl_xor(s, 1);
        s += __shfl_xor(s, 2);
        s += __shfl_xor(s, 4);
        s += __shfl_xor(s, 8);
        if (sub == 0) __builtin_nontemporal_store(s + b2s, out + e);
    }
}

extern "C" void kernel_launch(void* const* d_in, const int* in_sizes, int n_in,
                              void* d_out, int out_size, void* d_ws, size_t ws_size,
                              hipStream_t stream)
{
    const float* z_src = (const float*)d_in[0];
    const float* z_dst = (const float*)d_in[1];
    const int*   eidx  = (const int*)d_in[2];
    const float* W1    = (const float*)d_in[3];
    const float* b1    = (const float*)d_in[4];
    const float* W2    = (const float*)d_in[5];
    const float* b2    = (const float*)d_in[6];
    float*       outp  = (float*)d_out;

    const int Nn = in_sizes[0] / HDIM;    // 100000
    const int E  = in_sizes[2] / 2;       // 2000000

    unsigned short* Abuf = (unsigned short*)d_ws;
    unsigned short* Bbuf = Abuf + (size_t)Nn * HDIM;
    unsigned short* Wt   = Bbuf + (size_t)Nn * HDIM;

    convert_w1<<<128, 256, 0, stream>>>(W1, Wt);

    const int tiles = (Nn + 63) >> 6;     // 1563
    node_gemm_v6<<<2 * tiles, 256, 0, stream>>>(
        z_src, z_dst, Wt, b1, Abuf, Bbuf, Nn, tiles);

    edge_decode_bf16<<<8192, 256, 0, stream>>>(Abuf, Bbuf, eidx, W2, b2, outp, E);
}